// Round 1
// baseline (1206.565 us; speedup 1.0000x reference)
//
#include <hip/hip_runtime.h>

constexpr int N  = 100000;   // nodes
constexpr int E  = 625000;   // edges
constexpr int DF = 128;      // feature dim
// K = 2*DF = 256, OUT = 128

// ---------------- zero workspace ----------------
__global__ __launch_bounds__(256) void zero_ws(float4* __restrict__ p, int n4) {
    int i = blockIdx.x * blockDim.x + threadIdx.x;
    int stride = gridDim.x * blockDim.x;
    for (; i < n4; i += stride) p[i] = float4{0.f, 0.f, 0.f, 0.f};
}

// ---------------- edge scatter: segsum += feature[src]*w, cnt[dst] += 1 ----------------
__global__ __launch_bounds__(256) void edge_scatter(
    const float* __restrict__ feature, const float* __restrict__ rw,
    const int* __restrict__ dst, const int* __restrict__ src,
    float* __restrict__ segsum, float* __restrict__ cnt)
{
    int g = blockIdx.x * 256 + threadIdx.x;       // E*32 = 20,000,000 fits int
    if (g >= E * 32) return;
    int e = g >> 5, c = g & 31;
    int d = dst[e], s = src[e];
    float w = rw[e];
    float4 f = reinterpret_cast<const float4*>(feature)[s * 32 + c];
    float* o = segsum + (size_t)d * 128 + c * 4;
    atomicAdd(o + 0, f.x * w);
    atomicAdd(o + 1, f.y * w);
    atomicAdd(o + 2, f.z * w);
    atomicAdd(o + 3, f.w * w);
    if (c == 0) atomicAdd(cnt + d, 1.0f);
}

// ---------------- fused concat + GEMM: out = [feature, segsum/max(cnt,1)] @ W + b ----------------
__global__ __launch_bounds__(256) void sage_gemm(
    const float* __restrict__ feature, const float* __restrict__ segsum,
    const float* __restrict__ cnt, const float* __restrict__ W,
    const float* __restrict__ bias, float* __restrict__ out)
{
    __shared__ float As[64][68];    // A^T: As[k][row]; stride 68 floats = 272B (16B-aligned rows)
    __shared__ float Ws[64][128];   // W tile

    const int tid = threadIdx.x;
    const int tx = tid & 15;        // column group: cols tx*4..+3 and 64+tx*4..+3
    const int ty = tid >> 4;        // row group: rows ty*4..+3
    const int rowBase = blockIdx.x * 64;

    float acc[4][8];
    #pragma unroll
    for (int r = 0; r < 4; ++r)
        #pragma unroll
        for (int c = 0; c < 8; ++c) acc[r][c] = 0.f;

    for (int kc = 0; kc < 4; ++kc) {
        // ---- stage A tile (64 rows x 64 k), transposed ----
        {
            const int kk4 = (tid & 15) * 4;
            #pragma unroll
            for (int it = 0; it < 4; ++it) {
                int r = (tid >> 4) + it * 16;
                int row = rowBase + r;
                float4 v = {0.f, 0.f, 0.f, 0.f};
                if (row < N) {
                    int kglob = kc * 64 + kk4;
                    if (kglob < DF) {
                        v = *reinterpret_cast<const float4*>(&feature[(size_t)row * DF + kglob]);
                    } else {
                        float inv = 1.0f / fmaxf(cnt[row], 1.0f);
                        v = *reinterpret_cast<const float4*>(&segsum[(size_t)row * DF + (kglob - DF)]);
                        v.x *= inv; v.y *= inv; v.z *= inv; v.w *= inv;
                    }
                }
                As[kk4 + 0][r] = v.x;
                As[kk4 + 1][r] = v.y;
                As[kk4 + 2][r] = v.z;
                As[kk4 + 3][r] = v.w;
            }
        }
        // ---- stage W tile (64 k x 128 cols) ----
        {
            #pragma unroll
            for (int it = 0; it < 8; ++it) {
                int idx = tid + it * 256;          // float4 index, 0..2047
                int kk = idx >> 5;
                int c4 = (idx & 31) * 4;
                float4 v = *reinterpret_cast<const float4*>(&W[(size_t)(kc * 64 + kk) * 128 + c4]);
                *reinterpret_cast<float4*>(&Ws[kk][c4]) = v;
            }
        }
        __syncthreads();

        #pragma unroll 8
        for (int kk = 0; kk < 64; ++kk) {
            float4 a  = *reinterpret_cast<const float4*>(&As[kk][ty * 4]);
            float4 w0 = *reinterpret_cast<const float4*>(&Ws[kk][tx * 4]);
            float4 w1 = *reinterpret_cast<const float4*>(&Ws[kk][64 + tx * 4]);
            float av[4] = {a.x, a.y, a.z, a.w};
            float wv[8] = {w0.x, w0.y, w0.z, w0.w, w1.x, w1.y, w1.z, w1.w};
            #pragma unroll
            for (int r = 0; r < 4; ++r)
                #pragma unroll
                for (int c = 0; c < 8; ++c)
                    acc[r][c] = fmaf(av[r], wv[c], acc[r][c]);
        }
        __syncthreads();
    }

    // ---- epilogue: add bias, store ----
    float4 b0 = *reinterpret_cast<const float4*>(&bias[tx * 4]);
    float4 b1 = *reinterpret_cast<const float4*>(&bias[64 + tx * 4]);
    #pragma unroll
    for (int r = 0; r < 4; ++r) {
        int row = rowBase + ty * 4 + r;
        if (row < N) {
            float4 o0 = {acc[r][0] + b0.x, acc[r][1] + b0.y, acc[r][2] + b0.z, acc[r][3] + b0.w};
            float4 o1 = {acc[r][4] + b1.x, acc[r][5] + b1.y, acc[r][6] + b1.z, acc[r][7] + b1.w};
            *reinterpret_cast<float4*>(&out[(size_t)row * 128 + tx * 4]) = o0;
            *reinterpret_cast<float4*>(&out[(size_t)row * 128 + 64 + tx * 4]) = o1;
        }
    }
}

extern "C" void kernel_launch(void* const* d_in, const int* in_sizes, int n_in,
                              void* d_out, int out_size, void* d_ws, size_t ws_size,
                              hipStream_t stream) {
    const float* feature = (const float*)d_in[0];
    const float* rw      = (const float*)d_in[1];
    const float* W       = (const float*)d_in[2];
    const float* bias    = (const float*)d_in[3];
    const int*   ridx    = (const int*)d_in[4];
    const int*   dst     = ridx;        // row 0: destination/segment ids
    const int*   src     = ridx + E;    // row 1: source/gather ids
    float* out = (float*)d_out;

    float* segsum = (float*)d_ws;                     // [N*128]
    float* cnt    = segsum + (size_t)N * DF;          // [N]

    int n4 = (N * DF + N + 3) / 4;                    // float4 count to zero
    zero_ws<<<2048, 256, 0, stream>>>((float4*)d_ws, n4);

    edge_scatter<<<(E * 32 + 255) / 256, 256, 0, stream>>>(feature, rw, dst, src, segsum, cnt);

    sage_gemm<<<(N + 63) / 64, 256, 0, stream>>>(feature, segsum, cnt, W, bias, out);
}

// Round 2
// 257.127 us; speedup vs baseline: 4.6925x; 4.6925x over previous
//
#include <hip/hip_runtime.h>

constexpr int N  = 100000;   // nodes
constexpr int E  = 625000;   // edges
constexpr int DF = 128;      // feature dim
// K = 2*DF = 256, OUT = 128

// ---------------- zero int region (hist + fill) ----------------
__global__ __launch_bounds__(256) void zero_ints(int* __restrict__ p, int n) {
    int i = blockIdx.x * blockDim.x + threadIdx.x;
    int stride = gridDim.x * blockDim.x;
    for (; i < n; i += stride) p[i] = 0;
}

// ---------------- histogram of dst ----------------
__global__ __launch_bounds__(256) void hist_k(const int* __restrict__ dst, int* __restrict__ hist) {
    int e = blockIdx.x * 256 + threadIdx.x;
    if (e < E) atomicAdd(&hist[dst[e]], 1);
}

// ---------------- exclusive scan, step 1: per-1024-chunk ----------------
__global__ __launch_bounds__(256) void scan_blocks(const int* __restrict__ hist,
                                                   int* __restrict__ offs,
                                                   int* __restrict__ bsum, int n) {
    __shared__ int wsum[4];
    int tid = threadIdx.x;
    int base = blockIdx.x * 1024 + tid * 4;
    int v[4];
    #pragma unroll
    for (int j = 0; j < 4; ++j) { int idx = base + j; v[j] = (idx < n) ? hist[idx] : 0; }
    int ts = v[0] + v[1] + v[2] + v[3];
    int lane = tid & 63;
    int incl = ts;
    #pragma unroll
    for (int d = 1; d < 64; d <<= 1) {
        int t = __shfl_up(incl, d, 64);
        if (lane >= d) incl += t;
    }
    int wid = tid >> 6;
    if (lane == 63) wsum[wid] = incl;
    __syncthreads();
    int woff = 0;
    #pragma unroll
    for (int w = 0; w < 4; ++w) if (w < wid) woff += wsum[w];
    int excl = woff + incl - ts;
    int run = excl;
    #pragma unroll
    for (int j = 0; j < 4; ++j) { int idx = base + j; if (idx < n) offs[idx] = run; run += v[j]; }
    if (tid == 255) bsum[blockIdx.x] = woff + incl;   // block total
}

// ---------------- scan step 2: scan the 98 chunk sums (one block) ----------------
__global__ __launch_bounds__(128) void scan_bsum(int* __restrict__ bsum, int nb) {
    __shared__ int tmp[128];
    int tid = threadIdx.x;
    int v = (tid < nb) ? bsum[tid] : 0;
    int acc = v;
    tmp[tid] = acc;
    __syncthreads();
    for (int d = 1; d < 128; d <<= 1) {
        int t = (tid >= d) ? tmp[tid - d] : 0;
        __syncthreads();
        acc += t;
        tmp[tid] = acc;
        __syncthreads();
    }
    if (tid < nb) bsum[tid] = acc - v;   // exclusive
}

// ---------------- scan step 3: add chunk offsets ----------------
__global__ __launch_bounds__(256) void scan_add(int* __restrict__ offs, const int* __restrict__ bsum, int n) {
    int idx = blockIdx.x * 256 + threadIdx.x;
    if (idx < n) offs[idx] += bsum[idx >> 10];
}

// ---------------- bucket scatter: counting-sort edge ids by dst ----------------
__global__ __launch_bounds__(256) void bucket_k(const int* __restrict__ dst,
                                                const int* __restrict__ offs,
                                                int* __restrict__ fill,
                                                int* __restrict__ edge_order) {
    int e = blockIdx.x * 256 + threadIdx.x;
    if (e < E) {
        int d = dst[e];
        int pos = offs[d] + atomicAdd(&fill[d], 1);
        edge_order[pos] = e;
    }
}

// ---------------- per-node aggregation: neigh_mean[node] = mean(feature[src]*w) ----------------
__global__ __launch_bounds__(256) void aggregate(
    const float* __restrict__ feature, const float* __restrict__ rw,
    const int* __restrict__ src, const int* __restrict__ edge_order,
    const int* __restrict__ offs, const int* __restrict__ hist,
    float* __restrict__ neigh_mean)
{
    int node = blockIdx.x * 4 + (threadIdx.x >> 6);
    if (node >= N) return;
    int lane = threadIdx.x & 63;
    int half = lane >> 5;      // lanes 0-31: even edges, 32-63: odd edges
    int slot = lane & 31;      // float4 slot within the 128-float row
    int off = offs[node], deg = hist[node];
    float4 acc = {0.f, 0.f, 0.f, 0.f};
    for (int i = half; i < deg; i += 2) {
        int e = edge_order[off + i];
        int s = src[e];
        float w = rw[e];
        float4 f = reinterpret_cast<const float4*>(feature)[(size_t)s * 32 + slot];
        acc.x = fmaf(f.x, w, acc.x);
        acc.y = fmaf(f.y, w, acc.y);
        acc.z = fmaf(f.z, w, acc.z);
        acc.w = fmaf(f.w, w, acc.w);
    }
    acc.x += __shfl_xor(acc.x, 32, 64);
    acc.y += __shfl_xor(acc.y, 32, 64);
    acc.z += __shfl_xor(acc.z, 32, 64);
    acc.w += __shfl_xor(acc.w, 32, 64);
    if (half == 0) {
        float inv = 1.0f / fmaxf((float)deg, 1.0f);
        acc.x *= inv; acc.y *= inv; acc.z *= inv; acc.w *= inv;
        reinterpret_cast<float4*>(neigh_mean)[(size_t)node * 32 + slot] = acc;
    }
}

// ---------------- fused concat + GEMM: out = [feature, neigh_mean] @ W + b ----------------
__global__ __launch_bounds__(256) void sage_gemm(
    const float* __restrict__ feature, const float* __restrict__ neigh_mean,
    const float* __restrict__ W, const float* __restrict__ bias,
    float* __restrict__ out)
{
    __shared__ float As[64][68];    // A^T: As[k][row]; stride 68 floats (16B-aligned rows)
    __shared__ float Ws[64][128];   // W tile

    const int tid = threadIdx.x;
    const int tx = tid & 15;        // cols tx*4..+3 and 64+tx*4..+3
    const int ty = tid >> 4;        // rows ty*4..+3
    const int rowBase = blockIdx.x * 64;

    float acc[4][8];
    #pragma unroll
    for (int r = 0; r < 4; ++r)
        #pragma unroll
        for (int c = 0; c < 8; ++c) acc[r][c] = 0.f;

    for (int kc = 0; kc < 4; ++kc) {
        // ---- stage A tile (64 rows x 64 k), transposed ----
        {
            const int kk4 = (tid & 15) * 4;
            #pragma unroll
            for (int it = 0; it < 4; ++it) {
                int r = (tid >> 4) + it * 16;
                int row = rowBase + r;
                float4 v = {0.f, 0.f, 0.f, 0.f};
                if (row < N) {
                    int kglob = kc * 64 + kk4;
                    const float* srcp = (kglob < DF)
                        ? &feature[(size_t)row * DF + kglob]
                        : &neigh_mean[(size_t)row * DF + (kglob - DF)];
                    v = *reinterpret_cast<const float4*>(srcp);
                }
                As[kk4 + 0][r] = v.x;
                As[kk4 + 1][r] = v.y;
                As[kk4 + 2][r] = v.z;
                As[kk4 + 3][r] = v.w;
            }
        }
        // ---- stage W tile (64 k x 128 cols) ----
        {
            #pragma unroll
            for (int it = 0; it < 8; ++it) {
                int idx = tid + it * 256;          // float4 index, 0..2047
                int kk = idx >> 5;
                int c4 = (idx & 31) * 4;
                float4 v = *reinterpret_cast<const float4*>(&W[(size_t)(kc * 64 + kk) * 128 + c4]);
                *reinterpret_cast<float4*>(&Ws[kk][c4]) = v;
            }
        }
        __syncthreads();

        #pragma unroll 8
        for (int kk = 0; kk < 64; ++kk) {
            float4 a  = *reinterpret_cast<const float4*>(&As[kk][ty * 4]);
            float4 w0 = *reinterpret_cast<const float4*>(&Ws[kk][tx * 4]);
            float4 w1 = *reinterpret_cast<const float4*>(&Ws[kk][64 + tx * 4]);
            float av[4] = {a.x, a.y, a.z, a.w};
            float wv[8] = {w0.x, w0.y, w0.z, w0.w, w1.x, w1.y, w1.z, w1.w};
            #pragma unroll
            for (int r = 0; r < 4; ++r)
                #pragma unroll
                for (int c = 0; c < 8; ++c)
                    acc[r][c] = fmaf(av[r], wv[c], acc[r][c]);
        }
        __syncthreads();
    }

    float4 b0 = *reinterpret_cast<const float4*>(&bias[tx * 4]);
    float4 b1 = *reinterpret_cast<const float4*>(&bias[64 + tx * 4]);
    #pragma unroll
    for (int r = 0; r < 4; ++r) {
        int row = rowBase + ty * 4 + r;
        if (row < N) {
            float4 o0 = {acc[r][0] + b0.x, acc[r][1] + b0.y, acc[r][2] + b0.z, acc[r][3] + b0.w};
            float4 o1 = {acc[r][4] + b1.x, acc[r][5] + b1.y, acc[r][6] + b1.z, acc[r][7] + b1.w};
            *reinterpret_cast<float4*>(&out[(size_t)row * 128 + tx * 4]) = o0;
            *reinterpret_cast<float4*>(&out[(size_t)row * 128 + 64 + tx * 4]) = o1;
        }
    }
}

extern "C" void kernel_launch(void* const* d_in, const int* in_sizes, int n_in,
                              void* d_out, int out_size, void* d_ws, size_t ws_size,
                              hipStream_t stream) {
    const float* feature = (const float*)d_in[0];
    const float* rw      = (const float*)d_in[1];
    const float* W       = (const float*)d_in[2];
    const float* bias    = (const float*)d_in[3];
    const int*   ridx    = (const int*)d_in[4];
    const int*   dst     = ridx;        // row 0: destination/segment ids
    const int*   src     = ridx + E;    // row 1: source/gather ids
    float* out = (float*)d_out;

    // ---- workspace layout ----
    float* neigh = (float*)d_ws;                        // [N*128] f32
    int* offs       = (int*)(neigh + (size_t)N * DF);   // [N]
    int* hist       = offs + N;                         // [N]
    int* fill       = hist + N;                         // [N]
    int* bsum       = fill + N;                         // [128]
    int* edge_order = bsum + 128;                       // [E]

    const int nChunks = (N + 1023) / 1024;              // 98

    zero_ints<<<512, 256, 0, stream>>>(hist, 2 * N);    // hist + fill (adjacent)
    hist_k<<<(E + 255) / 256, 256, 0, stream>>>(dst, hist);
    scan_blocks<<<nChunks, 256, 0, stream>>>(hist, offs, bsum, N);
    scan_bsum<<<1, 128, 0, stream>>>(bsum, nChunks);
    scan_add<<<(N + 255) / 256, 256, 0, stream>>>(offs, bsum, N);
    bucket_k<<<(E + 255) / 256, 256, 0, stream>>>(dst, offs, fill, edge_order);
    aggregate<<<(N + 3) / 4, 256, 0, stream>>>(feature, rw, src, edge_order, offs, hist, neigh);
    sage_gemm<<<(N + 63) / 64, 256, 0, stream>>>(feature, neigh, W, bias, out);
}

// Round 3
// 187.737 us; speedup vs baseline: 6.4269x; 1.3696x over previous
//
#include <hip/hip_runtime.h>

constexpr int N  = 100000;   // nodes
constexpr int E  = 625000;   // edges
constexpr int DF = 128;      // feature dim
// K = 2*DF = 256, OUT = 128

typedef __attribute__((ext_vector_type(8))) short bf16x8;
typedef __attribute__((ext_vector_type(4))) float f32x4;

__device__ inline short f2bf(float f) {
    union { float f; unsigned u; } a; a.f = f;
    unsigned r = a.u + 0x7FFF + ((a.u >> 16) & 1);   // round-nearest-even
    return (short)(r >> 16);
}

// byte-address swizzle within a 128B LDS row: spreads 16-row column reads over 8 slots
__device__ inline int swz(int row, int byteInRow) {
    return row * 128 + (byteInRow ^ ((row & 7) << 4));
}

// ---------------- zero int region (hist + fill) ----------------
__global__ __launch_bounds__(256) void zero_ints(int* __restrict__ p, int n) {
    int i = blockIdx.x * blockDim.x + threadIdx.x;
    int stride = gridDim.x * blockDim.x;
    for (; i < n; i += stride) p[i] = 0;
}

// ---------------- W transpose + bf16 convert: wtb[c][k] = bf16(W[k][c]) ----------------
__global__ __launch_bounds__(256) void wt_prep(const float* __restrict__ W, short* __restrict__ wtb) {
    int idx = blockIdx.x * 256 + threadIdx.x;        // 32768
    if (idx < 256 * 128) {
        int k = idx >> 7, c = idx & 127;             // coalesced read of W[k][c]
        wtb[c * 256 + k] = f2bf(W[idx]);
    }
}

// ---------------- histogram of dst ----------------
__global__ __launch_bounds__(256) void hist_k(const int* __restrict__ dst, int* __restrict__ hist) {
    int e = blockIdx.x * 256 + threadIdx.x;
    if (e < E) atomicAdd(&hist[dst[e]], 1);
}

// ---------------- exclusive scan, step 1: per-1024-chunk ----------------
__global__ __launch_bounds__(256) void scan_blocks(const int* __restrict__ hist,
                                                   int* __restrict__ offs,
                                                   int* __restrict__ bsum, int n) {
    __shared__ int wsum[4];
    int tid = threadIdx.x;
    int base = blockIdx.x * 1024 + tid * 4;
    int v[4];
    #pragma unroll
    for (int j = 0; j < 4; ++j) { int idx = base + j; v[j] = (idx < n) ? hist[idx] : 0; }
    int ts = v[0] + v[1] + v[2] + v[3];
    int lane = tid & 63;
    int incl = ts;
    #pragma unroll
    for (int d = 1; d < 64; d <<= 1) {
        int t = __shfl_up(incl, d, 64);
        if (lane >= d) incl += t;
    }
    int wid = tid >> 6;
    if (lane == 63) wsum[wid] = incl;
    __syncthreads();
    int woff = 0;
    #pragma unroll
    for (int w = 0; w < 4; ++w) if (w < wid) woff += wsum[w];
    int excl = woff + incl - ts;
    int run = excl;
    #pragma unroll
    for (int j = 0; j < 4; ++j) { int idx = base + j; if (idx < n) offs[idx] = run; run += v[j]; }
    if (tid == 255) bsum[blockIdx.x] = woff + incl;   // block total
}

// ---------------- scan step 2 ----------------
__global__ __launch_bounds__(128) void scan_bsum(int* __restrict__ bsum, int nb) {
    __shared__ int tmp[128];
    int tid = threadIdx.x;
    int v = (tid < nb) ? bsum[tid] : 0;
    int acc = v;
    tmp[tid] = acc;
    __syncthreads();
    for (int d = 1; d < 128; d <<= 1) {
        int t = (tid >= d) ? tmp[tid - d] : 0;
        __syncthreads();
        acc += t;
        tmp[tid] = acc;
        __syncthreads();
    }
    if (tid < nb) bsum[tid] = acc - v;   // exclusive
}

// ---------------- scan step 3 ----------------
__global__ __launch_bounds__(256) void scan_add(int* __restrict__ offs, const int* __restrict__ bsum, int n) {
    int idx = blockIdx.x * 256 + threadIdx.x;
    if (idx < n) offs[idx] += bsum[idx >> 10];
}

// ---------------- bucket scatter: sort (src, w) by dst ----------------
__global__ __launch_bounds__(256) void bucket_k(const int* __restrict__ dst,
                                                const int* __restrict__ src,
                                                const float* __restrict__ rw,
                                                const int* __restrict__ offs,
                                                int* __restrict__ fill,
                                                int* __restrict__ src_sorted,
                                                float* __restrict__ w_sorted) {
    int e = blockIdx.x * 256 + threadIdx.x;
    if (e < E) {
        int d = dst[e];
        int pos = offs[d] + atomicAdd(&fill[d], 1);
        src_sorted[pos] = src[e];
        w_sorted[pos] = rw[e];
    }
}

// ---------------- per-node aggregation ----------------
__global__ __launch_bounds__(256) void aggregate(
    const float* __restrict__ feature,
    const int* __restrict__ src_sorted, const float* __restrict__ w_sorted,
    const int* __restrict__ offs, const int* __restrict__ hist,
    float* __restrict__ neigh_mean)
{
    int node = blockIdx.x * 4 + (threadIdx.x >> 6);
    if (node >= N) return;
    int lane = threadIdx.x & 63;
    int half = lane >> 5;      // lanes 0-31: even edges, 32-63: odd edges
    int slot = lane & 31;      // float4 slot within the 128-float row
    int off = offs[node], deg = hist[node];
    float4 acc = {0.f, 0.f, 0.f, 0.f};
    int i = half;
    int s0 = 0; float w0 = 0.f;
    if (i < deg) { s0 = src_sorted[off + i]; w0 = w_sorted[off + i]; }
    while (i < deg) {
        int inext = i + 2;
        int s1 = 0; float w1 = 0.f;
        if (inext < deg) { s1 = src_sorted[off + inext]; w1 = w_sorted[off + inext]; }
        float4 f = reinterpret_cast<const float4*>(feature)[(size_t)s0 * 32 + slot];
        acc.x = fmaf(f.x, w0, acc.x);
        acc.y = fmaf(f.y, w0, acc.y);
        acc.z = fmaf(f.z, w0, acc.z);
        acc.w = fmaf(f.w, w0, acc.w);
        i = inext; s0 = s1; w0 = w1;
    }
    acc.x += __shfl_xor(acc.x, 32, 64);
    acc.y += __shfl_xor(acc.y, 32, 64);
    acc.z += __shfl_xor(acc.z, 32, 64);
    acc.w += __shfl_xor(acc.w, 32, 64);
    if (half == 0) {
        float inv = 1.0f / fmaxf((float)deg, 1.0f);
        acc.x *= inv; acc.y *= inv; acc.z *= inv; acc.w *= inv;
        reinterpret_cast<float4*>(neigh_mean)[(size_t)node * 32 + slot] = acc;
    }
}

// ---------------- MFMA concat-GEMM: out = bf16([feature, neigh]) @ bf16(W) + b ----------------
// BM=128, BN=128 (full), BK=64, 4 waves (2x2), 64x64 per wave, mfma_f32_16x16x32_bf16
__global__ __launch_bounds__(256) void sage_gemm(
    const float* __restrict__ feature, const float* __restrict__ neigh,
    const short* __restrict__ wtb,      // [128 cols][256 k] bf16
    const float* __restrict__ bias, float* __restrict__ out)
{
    __shared__ short As[128 * 64];   // [row][k] bf16, swizzled, 16 KB
    __shared__ short Bs[128 * 64];   // [col][k] bf16, swizzled, 16 KB

    const int tid = threadIdx.x;
    const int lane = tid & 63;
    const int wv = tid >> 6;
    const int wr = (wv >> 1) * 64;   // wave row offset in tile
    const int wc = (wv & 1) * 64;    // wave col offset in tile
    const int l15 = lane & 15;
    const int lg  = lane >> 4;       // 0..3
    const int rowBase = blockIdx.x * 128;

    f32x4 acc[4][4];
    #pragma unroll
    for (int mi = 0; mi < 4; ++mi)
        #pragma unroll
        for (int ni = 0; ni < 4; ++ni)
            acc[mi][ni] = f32x4{0.f, 0.f, 0.f, 0.f};

    for (int kc = 0; kc < 4; ++kc) {
        const int kglob = kc * 64;
        // ---- stage A: 128 rows x 64 k, f32 -> bf16, swizzled ----
        #pragma unroll
        for (int it = 0; it < 8; ++it) {
            int i = it * 256 + tid;          // float4 id, 0..2047
            int r  = i >> 4;                 // 0..127
            int f4 = i & 15;                 // k-offset f4*4
            int grow = rowBase + r;
            float4 v = {0.f, 0.f, 0.f, 0.f};
            if (grow < N) {
                int kg = kglob + f4 * 4;
                const float* p = (kg < DF) ? &feature[(size_t)grow * DF + kg]
                                           : &neigh[(size_t)grow * DF + (kg - DF)];
                v = *reinterpret_cast<const float4*>(p);
            }
            short4 h;
            h.x = f2bf(v.x); h.y = f2bf(v.y); h.z = f2bf(v.z); h.w = f2bf(v.w);
            *reinterpret_cast<short4*>(reinterpret_cast<char*>(As) + swz(r, f4 * 8)) = h;
        }
        // ---- stage B: 128 cols x 64 k from wtb (already bf16), swizzled ----
        #pragma unroll
        for (int it = 0; it < 4; ++it) {
            int i = it * 256 + tid;          // 16B id, 0..1023
            int c  = i >> 3;                 // col 0..127
            int k8 = i & 7;                  // 16B chunk within 128B row
            int4 v = *reinterpret_cast<const int4*>(&wtb[(size_t)c * 256 + kglob + k8 * 8]);
            *reinterpret_cast<int4*>(reinterpret_cast<char*>(Bs) + swz(c, k8 * 16)) = v;
        }
        __syncthreads();

        #pragma unroll
        for (int kk = 0; kk < 2; ++kk) {
            const int kb = kk * 64;          // byte offset of this K=32 step
            bf16x8 af[4], bfr[4];
            #pragma unroll
            for (int mi = 0; mi < 4; ++mi) {
                int row = wr + mi * 16 + l15;
                af[mi] = *reinterpret_cast<const bf16x8*>(
                    reinterpret_cast<const char*>(As) + swz(row, kb + lg * 16));
            }
            #pragma unroll
            for (int ni = 0; ni < 4; ++ni) {
                int col = wc + ni * 16 + l15;
                bfr[ni] = *reinterpret_cast<const bf16x8*>(
                    reinterpret_cast<const char*>(Bs) + swz(col, kb + lg * 16));
            }
            #pragma unroll
            for (int mi = 0; mi < 4; ++mi)
                #pragma unroll
                for (int ni = 0; ni < 4; ++ni)
                    acc[mi][ni] = __builtin_amdgcn_mfma_f32_16x16x32_bf16(
                        af[mi], bfr[ni], acc[mi][ni], 0, 0, 0);
        }
        __syncthreads();
    }

    // ---- epilogue: bias + store. D: col = lane&15, row = (lane>>4)*4 + q ----
    #pragma unroll
    for (int ni = 0; ni < 4; ++ni) {
        int col = wc + ni * 16 + l15;
        float bc = bias[col];
        #pragma unroll
        for (int mi = 0; mi < 4; ++mi) {
            #pragma unroll
            for (int q = 0; q < 4; ++q) {
                int grow = rowBase + wr + mi * 16 + lg * 4 + q;
                if (grow < N) out[(size_t)grow * 128 + col] = acc[mi][ni][q] + bc;
            }
        }
    }
}

extern "C" void kernel_launch(void* const* d_in, const int* in_sizes, int n_in,
                              void* d_out, int out_size, void* d_ws, size_t ws_size,
                              hipStream_t stream) {
    const float* feature = (const float*)d_in[0];
    const float* rw      = (const float*)d_in[1];
    const float* W       = (const float*)d_in[2];
    const float* bias    = (const float*)d_in[3];
    const int*   ridx    = (const int*)d_in[4];
    const int*   dst     = ridx;        // row 0: destination/segment ids
    const int*   src     = ridx + E;    // row 1: source/gather ids
    float* out = (float*)d_out;

    // ---- workspace layout ----
    float* neigh      = (float*)d_ws;                     // [N*128] f32
    int*   offs       = (int*)(neigh + (size_t)N * DF);   // [N]
    int*   hist       = offs + N;                         // [N]
    int*   fill       = hist + N;                         // [N]
    int*   bsum       = fill + N;                         // [128]
    int*   src_sorted = bsum + 128;                       // [E]
    float* w_sorted   = (float*)(src_sorted + E);         // [E]
    short* wtb        = (short*)(w_sorted + E);           // [128*256] bf16

    const int nChunks = (N + 1023) / 1024;                // 98

    zero_ints<<<512, 256, 0, stream>>>(hist, 2 * N);      // hist + fill (adjacent)
    wt_prep<<<128, 256, 0, stream>>>(W, wtb);
    hist_k<<<(E + 255) / 256, 256, 0, stream>>>(dst, hist);
    scan_blocks<<<nChunks, 256, 0, stream>>>(hist, offs, bsum, N);
    scan_bsum<<<1, 128, 0, stream>>>(bsum, nChunks);
    scan_add<<<(N + 255) / 256, 256, 0, stream>>>(offs, bsum, N);
    bucket_k<<<(E + 255) / 256, 256, 0, stream>>>(dst, src, rw, offs, fill, src_sorted, w_sorted);
    aggregate<<<(N + 3) / 4, 256, 0, stream>>>(feature, src_sorted, w_sorted, offs, hist, neigh);
    sage_gemm<<<(N + 127) / 128, 256, 0, stream>>>(feature, neigh, wtb, bias, out);
}

// Round 4
// 153.824 us; speedup vs baseline: 7.8438x; 1.2205x over previous
//
#include <hip/hip_runtime.h>

constexpr int N  = 100000;   // nodes
constexpr int E  = 625000;   // edges
constexpr int DF = 128;      // feature dim
// K = 2*DF = 256, OUT = 128

typedef __attribute__((ext_vector_type(8))) short bf16x8;
typedef __attribute__((ext_vector_type(4))) float f32x4;

__device__ inline unsigned short f2bf(float f) {
    union { float f; unsigned u; } a; a.f = f;
    unsigned r = a.u + 0x7FFF + ((a.u >> 16) & 1);   // round-nearest-even
    return (unsigned short)(r >> 16);
}
__device__ inline unsigned pk2(float lo, float hi) {
    return (unsigned)f2bf(lo) | ((unsigned)f2bf(hi) << 16);
}
__device__ inline float bflo(unsigned u) { return __uint_as_float(u << 16); }
__device__ inline float bfhi(unsigned u) { return __uint_as_float(u & 0xFFFF0000u); }

// byte-address swizzle within a 128B LDS row: spreads 16-row column reads over 8 slots
__device__ inline int swz(int row, int byteInRow) {
    return row * 128 + (byteInRow ^ ((row & 7) << 4));
}

// ---------------- fused prep: zero hist+fill, W->bf16 transposed, feature->bf16 ----------------
__global__ __launch_bounds__(256) void prep(
    const float* __restrict__ feature, const float* __restrict__ W,
    int* __restrict__ zero_region, unsigned short* __restrict__ wtb,
    unsigned short* __restrict__ fbf)
{
    int t = blockIdx.x * 256 + threadIdx.x;
    int stride = gridDim.x * 256;
    for (int i = t; i < 2 * N; i += stride) zero_region[i] = 0;
    for (int i = t; i < 256 * 128; i += stride) {
        int k = i >> 7, c = i & 127;                 // coalesced read of W[k][c]
        wtb[c * 256 + k] = f2bf(W[i]);
    }
    int n8 = N * DF / 8;
    for (int i = t; i < n8; i += stride) {
        float4 a = reinterpret_cast<const float4*>(feature)[2 * i];
        float4 b = reinterpret_cast<const float4*>(feature)[2 * i + 1];
        uint4 o;
        o.x = pk2(a.x, a.y); o.y = pk2(a.z, a.w);
        o.z = pk2(b.x, b.y); o.w = pk2(b.z, b.w);
        reinterpret_cast<uint4*>(fbf)[i] = o;
    }
}

// ---------------- histogram of dst ----------------
__global__ __launch_bounds__(256) void hist_k(const int* __restrict__ dst, int* __restrict__ hist) {
    int e = blockIdx.x * 256 + threadIdx.x;
    if (e < E) atomicAdd(&hist[dst[e]], 1);
}

// ---------------- exclusive scan, step 1: per-1024-chunk ----------------
__global__ __launch_bounds__(256) void scan_blocks(const int* __restrict__ hist,
                                                   int* __restrict__ offs,
                                                   int* __restrict__ bsum, int n) {
    __shared__ int wsum[4];
    int tid = threadIdx.x;
    int base = blockIdx.x * 1024 + tid * 4;
    int v[4];
    #pragma unroll
    for (int j = 0; j < 4; ++j) { int idx = base + j; v[j] = (idx < n) ? hist[idx] : 0; }
    int ts = v[0] + v[1] + v[2] + v[3];
    int lane = tid & 63;
    int incl = ts;
    #pragma unroll
    for (int d = 1; d < 64; d <<= 1) {
        int t = __shfl_up(incl, d, 64);
        if (lane >= d) incl += t;
    }
    int wid = tid >> 6;
    if (lane == 63) wsum[wid] = incl;
    __syncthreads();
    int woff = 0;
    #pragma unroll
    for (int w = 0; w < 4; ++w) if (w < wid) woff += wsum[w];
    int excl = woff + incl - ts;
    int run = excl;
    #pragma unroll
    for (int j = 0; j < 4; ++j) { int idx = base + j; if (idx < n) offs[idx] = run; run += v[j]; }
    if (tid == 255) bsum[blockIdx.x] = woff + incl;   // block total
}

// ---------------- scan step 2 ----------------
__global__ __launch_bounds__(128) void scan_bsum(int* __restrict__ bsum, int nb) {
    __shared__ int tmp[128];
    int tid = threadIdx.x;
    int v = (tid < nb) ? bsum[tid] : 0;
    int acc = v;
    tmp[tid] = acc;
    __syncthreads();
    for (int d = 1; d < 128; d <<= 1) {
        int t = (tid >= d) ? tmp[tid - d] : 0;
        __syncthreads();
        acc += t;
        tmp[tid] = acc;
        __syncthreads();
    }
    if (tid < nb) bsum[tid] = acc - v;   // exclusive
}

// ---------------- scan step 3 ----------------
__global__ __launch_bounds__(256) void scan_add(int* __restrict__ offs, const int* __restrict__ bsum, int n) {
    int idx = blockIdx.x * 256 + threadIdx.x;
    if (idx < n) offs[idx] += bsum[idx >> 10];
}

// ---------------- bucket scatter: sort packed (src, w) by dst ----------------
__global__ __launch_bounds__(256) void bucket_k(const int* __restrict__ dst,
                                                const int* __restrict__ src,
                                                const float* __restrict__ rw,
                                                const int* __restrict__ offs,
                                                int* __restrict__ fill,
                                                int2* __restrict__ edge_sw) {
    int e = blockIdx.x * 256 + threadIdx.x;
    if (e < E) {
        int d = dst[e];
        int pos = offs[d] + atomicAdd(&fill[d], 1);
        edge_sw[pos] = make_int2(src[e], __float_as_int(rw[e]));
    }
}

// ---------------- per-node aggregation: bf16 gathers, f32 accum, bf16 out ----------------
// one node per wave; 4 edge slots x 16 lanes x 16B (8 bf16) per edge row
__global__ __launch_bounds__(256) void aggregate(
    const unsigned short* __restrict__ fbf,
    const int2* __restrict__ edge_sw,
    const int* __restrict__ offs, const int* __restrict__ hist,
    unsigned short* __restrict__ nbf)
{
    int node = blockIdx.x * 4 + (threadIdx.x >> 6);
    if (node >= N) return;
    int lane = threadIdx.x & 63;
    int eslot = lane >> 4;       // 0..3: which edge of the group of 4
    int chunk = lane & 15;       // 16B chunk within the 256B bf16 row
    int off = offs[node], deg = hist[node];
    float acc[8];
    #pragma unroll
    for (int j = 0; j < 8; ++j) acc[j] = 0.f;

    int i = eslot;
    int2 sw = (i < deg) ? edge_sw[off + i] : make_int2(0, 0);
    while (i < deg) {
        int inext = i + 4;
        int2 swn = (inext < deg) ? edge_sw[off + inext] : make_int2(0, 0);
        uint4 f = reinterpret_cast<const uint4*>(fbf)[(size_t)sw.x * 16 + chunk];
        float w = __int_as_float(sw.y);
        acc[0] = fmaf(bflo(f.x), w, acc[0]);
        acc[1] = fmaf(bfhi(f.x), w, acc[1]);
        acc[2] = fmaf(bflo(f.y), w, acc[2]);
        acc[3] = fmaf(bfhi(f.y), w, acc[3]);
        acc[4] = fmaf(bflo(f.z), w, acc[4]);
        acc[5] = fmaf(bfhi(f.z), w, acc[5]);
        acc[6] = fmaf(bflo(f.w), w, acc[6]);
        acc[7] = fmaf(bfhi(f.w), w, acc[7]);
        i = inext; sw = swn;
    }
    // reduce the 4 edge slots
    #pragma unroll
    for (int j = 0; j < 8; ++j) {
        acc[j] += __shfl_xor(acc[j], 16, 64);
        acc[j] += __shfl_xor(acc[j], 32, 64);
    }
    if (lane < 16) {
        float inv = 1.0f / fmaxf((float)deg, 1.0f);
        uint4 o;
        o.x = pk2(acc[0] * inv, acc[1] * inv);
        o.y = pk2(acc[2] * inv, acc[3] * inv);
        o.z = pk2(acc[4] * inv, acc[5] * inv);
        o.w = pk2(acc[6] * inv, acc[7] * inv);
        reinterpret_cast<uint4*>(nbf)[(size_t)node * 16 + chunk] = o;
    }
}

// ---------------- MFMA concat-GEMM: out = [fbf, nbf] @ wtb + b ----------------
// BM=128, BN=128 (full), BK=64, 4 waves (2x2), 64x64 per wave, mfma_f32_16x16x32_bf16
__global__ __launch_bounds__(256) void sage_gemm(
    const unsigned short* __restrict__ fbf, const unsigned short* __restrict__ nbf,
    const unsigned short* __restrict__ wtb,   // [128 cols][256 k] bf16
    const float* __restrict__ bias, float* __restrict__ out)
{
    __shared__ short As[128 * 64];   // [row][k] bf16, swizzled, 16 KB
    __shared__ short Bs[128 * 64];   // [col][k] bf16, swizzled, 16 KB

    const int tid = threadIdx.x;
    const int lane = tid & 63;
    const int wv = tid >> 6;
    const int wr = (wv >> 1) * 64;   // wave row offset in tile
    const int wc = (wv & 1) * 64;    // wave col offset in tile
    const int l15 = lane & 15;
    const int lg  = lane >> 4;       // 0..3
    const int rowBase = blockIdx.x * 128;

    f32x4 acc[4][4];
    #pragma unroll
    for (int mi = 0; mi < 4; ++mi)
        #pragma unroll
        for (int ni = 0; ni < 4; ++ni)
            acc[mi][ni] = f32x4{0.f, 0.f, 0.f, 0.f};

    #pragma unroll
    for (int kc = 0; kc < 4; ++kc) {
        const int kglob = kc * 64;
        const unsigned short* Aap = (kc < 2) ? fbf : nbf;
        const int kbase = (kc & 1) * 64;
        // ---- stage A: 128 rows x 64 k bf16, swizzled; 1024 16B chunks ----
        #pragma unroll
        for (int it = 0; it < 4; ++it) {
            int i = it * 256 + tid;          // 16B id
            int r  = i >> 3;                 // row 0..127
            int c8 = i & 7;                  // k-offset c8*8
            int grow = rowBase + r;
            int4 v = {0, 0, 0, 0};
            if (grow < N)
                v = *reinterpret_cast<const int4*>(&Aap[(size_t)grow * DF + kbase + c8 * 8]);
            *reinterpret_cast<int4*>(reinterpret_cast<char*>(As) + swz(r, c8 * 16)) = v;
        }
        // ---- stage B: 128 cols x 64 k from wtb, swizzled ----
        #pragma unroll
        for (int it = 0; it < 4; ++it) {
            int i = it * 256 + tid;
            int c  = i >> 3;
            int k8 = i & 7;
            int4 v = *reinterpret_cast<const int4*>(&wtb[(size_t)c * 256 + kglob + k8 * 8]);
            *reinterpret_cast<int4*>(reinterpret_cast<char*>(Bs) + swz(c, k8 * 16)) = v;
        }
        __syncthreads();

        #pragma unroll
        for (int kk = 0; kk < 2; ++kk) {
            const int kb = kk * 64;          // byte offset of this K=32 step
            bf16x8 af[4], bfr[4];
            #pragma unroll
            for (int mi = 0; mi < 4; ++mi) {
                int row = wr + mi * 16 + l15;
                af[mi] = *reinterpret_cast<const bf16x8*>(
                    reinterpret_cast<const char*>(As) + swz(row, kb + lg * 16));
            }
            #pragma unroll
            for (int ni = 0; ni < 4; ++ni) {
                int col = wc + ni * 16 + l15;
                bfr[ni] = *reinterpret_cast<const bf16x8*>(
                    reinterpret_cast<const char*>(Bs) + swz(col, kb + lg * 16));
            }
            #pragma unroll
            for (int mi = 0; mi < 4; ++mi)
                #pragma unroll
                for (int ni = 0; ni < 4; ++ni)
                    acc[mi][ni] = __builtin_amdgcn_mfma_f32_16x16x32_bf16(
                        af[mi], bfr[ni], acc[mi][ni], 0, 0, 0);
        }
        __syncthreads();
    }

    // ---- epilogue: bias + store. D: col = lane&15, row = (lane>>4)*4 + q ----
    #pragma unroll
    for (int ni = 0; ni < 4; ++ni) {
        int col = wc + ni * 16 + l15;
        float bc = bias[col];
        #pragma unroll
        for (int mi = 0; mi < 4; ++mi) {
            #pragma unroll
            for (int q = 0; q < 4; ++q) {
                int grow = rowBase + wr + mi * 16 + lg * 4 + q;
                if (grow < N) out[(size_t)grow * 128 + col] = acc[mi][ni][q] + bc;
            }
        }
    }
}

extern "C" void kernel_launch(void* const* d_in, const int* in_sizes, int n_in,
                              void* d_out, int out_size, void* d_ws, size_t ws_size,
                              hipStream_t stream) {
    const float* feature = (const float*)d_in[0];
    const float* rw      = (const float*)d_in[1];
    const float* W       = (const float*)d_in[2];
    const float* bias    = (const float*)d_in[3];
    const int*   ridx    = (const int*)d_in[4];
    const int*   dst     = ridx;        // row 0: destination/segment ids
    const int*   src     = ridx + E;    // row 1: source/gather ids
    float* out = (float*)d_out;

    // ---- workspace layout (16B-aligned blocks first) ----
    unsigned short* fbf = (unsigned short*)d_ws;          // [N*128] bf16, 25.6 MB
    unsigned short* nbf = fbf + (size_t)N * DF;           // [N*128] bf16, 25.6 MB
    int2* edge_sw       = (int2*)(nbf + (size_t)N * DF);  // [E], 5 MB
    int*  offs          = (int*)(edge_sw + E);            // [N]
    int*  hist          = offs + N;                       // [N]
    int*  fill          = hist + N;                       // [N]
    int*  bsum          = fill + N;                       // [128]
    unsigned short* wtb = (unsigned short*)(bsum + 128);  // [128*256] bf16

    const int nChunks = (N + 1023) / 1024;                // 98

    prep<<<1280, 256, 0, stream>>>(feature, W, hist, wtb, fbf);   // zeros hist+fill
    hist_k<<<(E + 255) / 256, 256, 0, stream>>>(dst, hist);
    scan_blocks<<<nChunks, 256, 0, stream>>>(hist, offs, bsum, N);
    scan_bsum<<<1, 128, 0, stream>>>(bsum, nChunks);
    scan_add<<<(N + 255) / 256, 256, 0, stream>>>(offs, bsum, N);
    bucket_k<<<(E + 255) / 256, 256, 0, stream>>>(dst, src, rw, offs, fill, edge_sw);
    aggregate<<<(N + 3) / 4, 256, 0, stream>>>(fbf, edge_sw, offs, hist, nbf);
    sage_gemm<<<(N + 127) / 128, 256, 0, stream>>>(fbf, nbf, wtb, bias, out);
}